// Round 5
// baseline (133.756 us; speedup 1.0000x reference)
//
#include <hip/hip_runtime.h>
#include <hip/hip_bf16.h>

#define BATCH 4096
#define DIM   128
#define NT    32   // 4096 / 128 tiles per dimension
#define NBLK  (NT * NT)
// TEMP = 0.25 -> 1/T = 4; 4*log2(e):
#define EXP_SCALE 5.770780163555854f

typedef __bf16 bf16_t;
typedef __bf16 bf16x8 __attribute__((ext_vector_type(8)));
typedef float  f32x4  __attribute__((ext_vector_type(4)));

// ---------------------------------------------------------------------------
// Kernel A: normalize emb_i/emb_j rows (fp32 math) -> bf16 zi/zj, pos[k] =
// cos-sim. 16-lane groups, 8 floats/lane, 16 rows per block per matrix.
// Blocks 0..7 zero the denominators; block 8 zeroes the completion counter.
// ---------------------------------------------------------------------------
__global__ __launch_bounds__(256) void normalize_kernel(
    const float* __restrict__ emb_i, const float* __restrict__ emb_j,
    bf16_t* __restrict__ zi, bf16_t* __restrict__ zj, float* __restrict__ pos,
    float* __restrict__ denoms /* 8192 floats */, unsigned int* __restrict__ counter)
{
    const int tid = threadIdx.x;
    if (blockIdx.x < 8) {
        int idx = (blockIdx.x * 256 + tid) * 4;
        *(float4*)&denoms[idx] = make_float4(0.f, 0.f, 0.f, 0.f);
    }
    if (blockIdx.x == 8 && tid == 0) *counter = 0u;

    const int g  = tid >> 4;   // group 0..15 -> row within block
    const int gl = tid & 15;   // lane in group, holds 8 floats
    const int k  = blockIdx.x * 16 + g;

    const float4* pi4 = (const float4*)(emb_i + (size_t)k * DIM);
    const float4* pj4 = (const float4*)(emb_j + (size_t)k * DIM);
    float4 a0 = pi4[gl * 2], a1 = pi4[gl * 2 + 1];
    float4 b0 = pj4[gl * 2], b1 = pj4[gl * 2 + 1];

    float sii = a0.x*a0.x + a0.y*a0.y + a0.z*a0.z + a0.w*a0.w
              + a1.x*a1.x + a1.y*a1.y + a1.z*a1.z + a1.w*a1.w;
    float sjj = b0.x*b0.x + b0.y*b0.y + b0.z*b0.z + b0.w*b0.w
              + b1.x*b1.x + b1.y*b1.y + b1.z*b1.z + b1.w*b1.w;
    float sij = a0.x*b0.x + a0.y*b0.y + a0.z*b0.z + a0.w*b0.w
              + a1.x*b1.x + a1.y*b1.y + a1.z*b1.z + a1.w*b1.w;
#pragma unroll
    for (int m = 1; m < 16; m <<= 1) {
        sii += __shfl_xor(sii, m);
        sjj += __shfl_xor(sjj, m);
        sij += __shfl_xor(sij, m);
    }
    float inv_i = 1.0f / fmaxf(sqrtf(sii), 1e-12f);
    float inv_j = 1.0f / fmaxf(sqrtf(sjj), 1e-12f);

    bf16x8 oi, oj;
    oi[0] = (bf16_t)(a0.x*inv_i); oi[1] = (bf16_t)(a0.y*inv_i);
    oi[2] = (bf16_t)(a0.z*inv_i); oi[3] = (bf16_t)(a0.w*inv_i);
    oi[4] = (bf16_t)(a1.x*inv_i); oi[5] = (bf16_t)(a1.y*inv_i);
    oi[6] = (bf16_t)(a1.z*inv_i); oi[7] = (bf16_t)(a1.w*inv_i);
    oj[0] = (bf16_t)(b0.x*inv_j); oj[1] = (bf16_t)(b0.y*inv_j);
    oj[2] = (bf16_t)(b0.z*inv_j); oj[3] = (bf16_t)(b0.w*inv_j);
    oj[4] = (bf16_t)(b1.x*inv_j); oj[5] = (bf16_t)(b1.y*inv_j);
    oj[6] = (bf16_t)(b1.z*inv_j); oj[7] = (bf16_t)(b1.w*inv_j);
    *(bf16x8*)(zi + (size_t)k * DIM + gl * 8) = oi;
    *(bf16x8*)(zj + (size_t)k * DIM + gl * 8) = oj;

    if (gl == 0) pos[k] = sij * inv_i * inv_j;
}

// ---------------------------------------------------------------------------
// Kernel B: 128x128 tile of S = Zi * Zj^T per block (grid 32x32).
// A-fragments loaded directly global->VGPR (L2-resident, 64B chunks/row);
// only zj staged in LDS (padded 128->136: row stride 272 B = free 2-way
// conflicts, 16B-aligned). bf16 MFMA 16x16x32, K=128. Epilogue: e=exp(4*s),
// row sums complete per-wave (shfl), col sums cross-wave via LDS; atomicAdd
// into pre-zeroed denoms. Last block (device counter) computes the loss.
// ---------------------------------------------------------------------------
__global__ __launch_bounds__(256) void gemm_exp_kernel(
    const bf16_t* __restrict__ zi, const bf16_t* __restrict__ zj,
    float* __restrict__ denoms, const float* __restrict__ pos,
    unsigned int* __restrict__ counter, float* __restrict__ out)
{
    __shared__ __align__(16) bf16_t zj_s[128][136];
    __shared__ float colRed[4][128];
    __shared__ bool isLast;

    float* rowDenom = denoms;
    float* colDenom = denoms + BATCH;

    const int tid = threadIdx.x;
    const int ti = blockIdx.x, tj = blockIdx.y;
    const int wave = tid >> 6;
    const int lane = tid & 63;
    const int l15  = lane & 15;
    const int quad = lane >> 4;

    // A-fragments straight from global: lane (l15,quad) reads row
    // (wave*2+rt)*16+l15 at element ks*32+quad*8 (16 B each, 8 loads).
    bf16x8 afrag[2][4];
    {
        const bf16_t* base = zi + (size_t)(ti * 128) * DIM;
#pragma unroll
        for (int rt = 0; rt < 2; ++rt)
#pragma unroll
            for (int ks = 0; ks < 4; ++ks)
                afrag[rt][ks] = *(const bf16x8*)(
                    base + (size_t)((wave * 2 + rt) * 16 + l15) * DIM + ks * 32 + quad * 8);
    }

    // Stage zj tile into LDS: 2048 16B-chunks, 8 iters.
#pragma unroll
    for (int it = 0; it < 8; ++it) {
        int c = it * 256 + tid;
        int row = c >> 4;
        int col = (c & 15) << 3;
        *(uint4*)&zj_s[row][col] =
            *(const uint4*)(zj + ((size_t)(tj * 128 + row)) * DIM + col);
    }
    __syncthreads();

    const f32x4 vzero = {0.f, 0.f, 0.f, 0.f};
    f32x4 acc[2][8];
#pragma unroll
    for (int rt = 0; rt < 2; ++rt)
#pragma unroll
        for (int ct = 0; ct < 8; ++ct) acc[rt][ct] = vzero;

#pragma unroll
    for (int ks = 0; ks < 4; ++ks) {
        int k0 = ks * 32 + quad * 8;
        bf16x8 bfrag[8];
#pragma unroll
        for (int ct = 0; ct < 8; ++ct)
            bfrag[ct] = *(const bf16x8*)&zj_s[ct * 16 + l15][k0];
#pragma unroll
        for (int rt = 0; rt < 2; ++rt)
#pragma unroll
            for (int ct = 0; ct < 8; ++ct)
                acc[rt][ct] = __builtin_amdgcn_mfma_f32_16x16x32_bf16(
                    afrag[rt][ks], bfrag[ct], acc[rt][ct], 0, 0, 0);
    }

    // Epilogue: exp and partial sums.
    float rowPart[2][4] = {{0.f, 0.f, 0.f, 0.f}, {0.f, 0.f, 0.f, 0.f}};
    float colPart[8]    = {0.f, 0.f, 0.f, 0.f, 0.f, 0.f, 0.f, 0.f};
#pragma unroll
    for (int rt = 0; rt < 2; ++rt)
#pragma unroll
        for (int ct = 0; ct < 8; ++ct)
#pragma unroll
            for (int r = 0; r < 4; ++r) {
                float e = exp2f(acc[rt][ct][r] * EXP_SCALE);
                rowPart[rt][r] += e;   // row = (wave*2+rt)*16 + quad*4 + r
                colPart[ct]    += e;   // col = ct*16 + l15
            }

    // Row sums: complete within a wave; one atomic per row per block.
#pragma unroll
    for (int rt = 0; rt < 2; ++rt)
#pragma unroll
        for (int r = 0; r < 4; ++r) {
            float v = rowPart[rt][r];
            v += __shfl_xor(v, 1);
            v += __shfl_xor(v, 2);
            v += __shfl_xor(v, 4);
            v += __shfl_xor(v, 8);
            if (l15 == 0) {
                int grow = ti * 128 + (wave * 2 + rt) * 16 + quad * 4 + r;
                atomicAdd(&rowDenom[grow], v);
            }
        }

    // Col sums: quad shfl-reduce, cross-wave LDS reduce, coalesced atomics.
#pragma unroll
    for (int ct = 0; ct < 8; ++ct) {
        float v = colPart[ct];
        v += __shfl_xor(v, 16);
        v += __shfl_xor(v, 32);
        if (quad == 0) colRed[wave][ct * 16 + l15] = v;
    }
    __syncthreads();
    if (tid < 128) {
        float s = colRed[0][tid] + colRed[1][tid] + colRed[2][tid] + colRed[3][tid];
        atomicAdd(&colDenom[tj * 128 + tid], s);
    }

    // ---- Last-block finalize ----
    __threadfence();
    __syncthreads();
    if (tid == 0) {
        unsigned int old = atomicAdd(counter, 1u);
        isLast = (old == NBLK - 1);
    }
    __syncthreads();
    if (!isLast) return;

    float accv = 0.f;
#pragma unroll
    for (int it = 0; it < 16; ++it) {
        int k = it * 256 + tid;
        float r = __hip_atomic_load(&rowDenom[k], __ATOMIC_RELAXED,
                                    __HIP_MEMORY_SCOPE_AGENT);
        float c = __hip_atomic_load(&colDenom[k], __ATOMIC_RELAXED,
                                    __HIP_MEMORY_SCOPE_AGENT);
        accv += logf(r) + logf(c) - 8.0f * pos[k];
    }
#pragma unroll
    for (int m = 1; m < 64; m <<= 1) accv += __shfl_xor(accv, m);
    if (lane == 0) colRed[0][wave] = accv;
    __syncthreads();
    if (tid == 0)
        out[0] = (colRed[0][0] + colRed[0][1] + colRed[0][2] + colRed[0][3])
                 * (1.0f / (2.0f * BATCH));
}

extern "C" void kernel_launch(void* const* d_in, const int* in_sizes, int n_in,
                              void* d_out, int out_size, void* d_ws, size_t ws_size,
                              hipStream_t stream) {
    const float* emb_i = (const float*)d_in[0];
    const float* emb_j = (const float*)d_in[1];
    float* out = (float*)d_out;

    char* ws = (char*)d_ws;
    bf16_t* zi     = (bf16_t*)(ws);                        // 1 MB
    bf16_t* zj     = (bf16_t*)(ws + (1u << 20));           // 1 MB
    float*  denoms = (float*)(ws + (2u << 20));            // 32 KB (row ++ col)
    float*  pos    = denoms + 2 * BATCH;                   // 16 KB
    unsigned int* counter = (unsigned int*)(pos + BATCH);  // 4 B

    normalize_kernel<<<BATCH / 16, 256, 0, stream>>>(emb_i, emb_j, zi, zj, pos,
                                                     denoms, counter);
    gemm_exp_kernel<<<dim3(NT, NT), 256, 0, stream>>>(zi, zj, denoms, pos,
                                                      counter, out);
}

// Round 6
// 77.551 us; speedup vs baseline: 1.7247x; 1.7247x over previous
//
#include <hip/hip_runtime.h>
#include <hip/hip_bf16.h>

#define BATCH 4096
#define DIM   128
#define NT    32   // 4096 / 128 tiles per dimension
// TEMP = 0.25 -> 1/T = 4; 4*log2(e):
#define EXP_SCALE 5.770780163555854f

typedef __bf16 bf16_t;
typedef __bf16 bf16x8 __attribute__((ext_vector_type(8)));
typedef float  f32x4  __attribute__((ext_vector_type(4)));

// ---------------------------------------------------------------------------
// Kernel A: normalize emb_i/emb_j rows (fp32 math) -> bf16 zi/zj, pos[k] =
// cos-sim. 16-lane groups, 8 floats/lane, 16 rows per block per matrix.
// Blocks 0..7 zero the denominators (replaces a memset dispatch).
// ---------------------------------------------------------------------------
__global__ __launch_bounds__(256) void normalize_kernel(
    const float* __restrict__ emb_i, const float* __restrict__ emb_j,
    bf16_t* __restrict__ zi, bf16_t* __restrict__ zj, float* __restrict__ pos,
    float* __restrict__ denoms /* 8192 floats */)
{
    const int tid = threadIdx.x;
    if (blockIdx.x < 8) {
        int idx = (blockIdx.x * 256 + tid) * 4;
        *(float4*)&denoms[idx] = make_float4(0.f, 0.f, 0.f, 0.f);
    }

    const int g  = tid >> 4;   // group 0..15 -> row within block
    const int gl = tid & 15;   // lane in group, holds 8 floats
    const int k  = blockIdx.x * 16 + g;

    const float4* pi4 = (const float4*)(emb_i + (size_t)k * DIM);
    const float4* pj4 = (const float4*)(emb_j + (size_t)k * DIM);
    float4 a0 = pi4[gl * 2], a1 = pi4[gl * 2 + 1];
    float4 b0 = pj4[gl * 2], b1 = pj4[gl * 2 + 1];

    float sii = a0.x*a0.x + a0.y*a0.y + a0.z*a0.z + a0.w*a0.w
              + a1.x*a1.x + a1.y*a1.y + a1.z*a1.z + a1.w*a1.w;
    float sjj = b0.x*b0.x + b0.y*b0.y + b0.z*b0.z + b0.w*b0.w
              + b1.x*b1.x + b1.y*b1.y + b1.z*b1.z + b1.w*b1.w;
    float sij = a0.x*b0.x + a0.y*b0.y + a0.z*b0.z + a0.w*b0.w
              + a1.x*b1.x + a1.y*b1.y + a1.z*b1.z + a1.w*b1.w;
#pragma unroll
    for (int m = 1; m < 16; m <<= 1) {
        sii += __shfl_xor(sii, m);
        sjj += __shfl_xor(sjj, m);
        sij += __shfl_xor(sij, m);
    }
    float inv_i = 1.0f / fmaxf(sqrtf(sii), 1e-12f);
    float inv_j = 1.0f / fmaxf(sqrtf(sjj), 1e-12f);

    bf16x8 oi, oj;
    oi[0] = (bf16_t)(a0.x*inv_i); oi[1] = (bf16_t)(a0.y*inv_i);
    oi[2] = (bf16_t)(a0.z*inv_i); oi[3] = (bf16_t)(a0.w*inv_i);
    oi[4] = (bf16_t)(a1.x*inv_i); oi[5] = (bf16_t)(a1.y*inv_i);
    oi[6] = (bf16_t)(a1.z*inv_i); oi[7] = (bf16_t)(a1.w*inv_i);
    oj[0] = (bf16_t)(b0.x*inv_j); oj[1] = (bf16_t)(b0.y*inv_j);
    oj[2] = (bf16_t)(b0.z*inv_j); oj[3] = (bf16_t)(b0.w*inv_j);
    oj[4] = (bf16_t)(b1.x*inv_j); oj[5] = (bf16_t)(b1.y*inv_j);
    oj[6] = (bf16_t)(b1.z*inv_j); oj[7] = (bf16_t)(b1.w*inv_j);
    *(bf16x8*)(zi + (size_t)k * DIM + gl * 8) = oi;
    *(bf16x8*)(zj + (size_t)k * DIM + gl * 8) = oj;

    if (gl == 0) pos[k] = sij * inv_i * inv_j;
}

// ---------------------------------------------------------------------------
// Kernel B: 128x128 tile of S = Zi * Zj^T per block (grid 32x32).
// A-fragments loaded directly global->VGPR (L2-resident; no intra-block
// reuse of A rows across waves, so LDS buys nothing for A). Only zj staged
// in LDS (4x cross-wave reuse; padded 128->136: row stride 272 B = free
// 2-way conflicts, 16B-aligned). bf16 MFMA 16x16x32, K=128.
// Epilogue: e = exp(4*s); row sums complete per-wave (shfl) -> 1 atomic per
// row; col sums cross-wave via LDS -> 1 coalesced atomic per col.
// NO device fences here — round 5 showed per-block __threadfence() forces
// L2 writeback/invalidate per block and thrashes the L2-resident tiles
// (gemm 8 -> 80 us). Finalize is its own dispatch instead.
// ---------------------------------------------------------------------------
__global__ __launch_bounds__(256) void gemm_exp_kernel(
    const bf16_t* __restrict__ zi, const bf16_t* __restrict__ zj,
    float* __restrict__ rowDenom, float* __restrict__ colDenom)
{
    __shared__ __align__(16) bf16_t zj_s[128][136];
    __shared__ float colRed[4][128];

    const int tid = threadIdx.x;
    const int ti = blockIdx.x, tj = blockIdx.y;
    const int wave = tid >> 6;
    const int lane = tid & 63;
    const int l15  = lane & 15;
    const int quad = lane >> 4;

    // A-fragments straight from global: lane (l15,quad) reads row
    // (wave*2+rt)*16+l15 at element ks*32+quad*8 (16 B each, 8 loads).
    bf16x8 afrag[2][4];
    {
        const bf16_t* base = zi + (size_t)(ti * 128) * DIM;
#pragma unroll
        for (int rt = 0; rt < 2; ++rt)
#pragma unroll
            for (int ks = 0; ks < 4; ++ks)
                afrag[rt][ks] = *(const bf16x8*)(
                    base + (size_t)((wave * 2 + rt) * 16 + l15) * DIM + ks * 32 + quad * 8);
    }

    // Stage zj tile into LDS: 2048 16B-chunks, 8 iters.
#pragma unroll
    for (int it = 0; it < 8; ++it) {
        int c = it * 256 + tid;
        int row = c >> 4;
        int col = (c & 15) << 3;
        *(uint4*)&zj_s[row][col] =
            *(const uint4*)(zj + ((size_t)(tj * 128 + row)) * DIM + col);
    }
    __syncthreads();

    const f32x4 vzero = {0.f, 0.f, 0.f, 0.f};
    f32x4 acc[2][8];
#pragma unroll
    for (int rt = 0; rt < 2; ++rt)
#pragma unroll
        for (int ct = 0; ct < 8; ++ct) acc[rt][ct] = vzero;

#pragma unroll
    for (int ks = 0; ks < 4; ++ks) {
        int k0 = ks * 32 + quad * 8;
        bf16x8 bfrag[8];
#pragma unroll
        for (int ct = 0; ct < 8; ++ct)
            bfrag[ct] = *(const bf16x8*)&zj_s[ct * 16 + l15][k0];
#pragma unroll
        for (int rt = 0; rt < 2; ++rt)
#pragma unroll
            for (int ct = 0; ct < 8; ++ct)
                acc[rt][ct] = __builtin_amdgcn_mfma_f32_16x16x32_bf16(
                    afrag[rt][ks], bfrag[ct], acc[rt][ct], 0, 0, 0);
    }

    // Epilogue: exp and partial sums.
    float rowPart[2][4] = {{0.f, 0.f, 0.f, 0.f}, {0.f, 0.f, 0.f, 0.f}};
    float colPart[8]    = {0.f, 0.f, 0.f, 0.f, 0.f, 0.f, 0.f, 0.f};
#pragma unroll
    for (int rt = 0; rt < 2; ++rt)
#pragma unroll
        for (int ct = 0; ct < 8; ++ct)
#pragma unroll
            for (int r = 0; r < 4; ++r) {
                float e = exp2f(acc[rt][ct][r] * EXP_SCALE);
                rowPart[rt][r] += e;   // row = (wave*2+rt)*16 + quad*4 + r
                colPart[ct]    += e;   // col = ct*16 + l15
            }

    // Row sums: complete within a wave; one atomic per row per block.
#pragma unroll
    for (int rt = 0; rt < 2; ++rt)
#pragma unroll
        for (int r = 0; r < 4; ++r) {
            float v = rowPart[rt][r];
            v += __shfl_xor(v, 1);
            v += __shfl_xor(v, 2);
            v += __shfl_xor(v, 4);
            v += __shfl_xor(v, 8);
            if (l15 == 0) {
                int grow = ti * 128 + (wave * 2 + rt) * 16 + quad * 4 + r;
                atomicAdd(&rowDenom[grow], v);
            }
        }

    // Col sums: quad shfl-reduce, cross-wave LDS reduce, coalesced atomics.
#pragma unroll
    for (int ct = 0; ct < 8; ++ct) {
        float v = colPart[ct];
        v += __shfl_xor(v, 16);
        v += __shfl_xor(v, 32);
        if (quad == 0) colRed[wave][ct * 16 + l15] = v;
    }
    __syncthreads();
    if (tid < 128) {
        float s = colRed[0][tid] + colRed[1][tid] + colRed[2][tid] + colRed[3][tid];
        atomicAdd(&colDenom[tj * 128 + tid], s);
    }
}

// ---------------------------------------------------------------------------
// Kernel C: loss = (1/2B) * sum_k [log rowDenom_k + log colDenom_k - 8*pos_k]
// Only 48 KB of reads -> single block is fine.
// ---------------------------------------------------------------------------
__global__ __launch_bounds__(256) void finalize_kernel(
    const float* __restrict__ denoms, const float* __restrict__ pos,
    float* __restrict__ out)
{
    const float* rowDenom = denoms;
    const float* colDenom = denoms + BATCH;
    int tid = threadIdx.x;
    float acc = 0.f;
#pragma unroll
    for (int it = 0; it < 16; ++it) {
        int k = it * 256 + tid;
        acc += logf(rowDenom[k]) + logf(colDenom[k]) - 8.0f * pos[k];
    }
#pragma unroll
    for (int m = 1; m < 64; m <<= 1) acc += __shfl_xor(acc, m);
    __shared__ float red[4];
    if ((tid & 63) == 0) red[tid >> 6] = acc;
    __syncthreads();
    if (tid == 0)
        out[0] = (red[0] + red[1] + red[2] + red[3]) * (1.0f / (2.0f * BATCH));
}

extern "C" void kernel_launch(void* const* d_in, const int* in_sizes, int n_in,
                              void* d_out, int out_size, void* d_ws, size_t ws_size,
                              hipStream_t stream) {
    const float* emb_i = (const float*)d_in[0];
    const float* emb_j = (const float*)d_in[1];
    float* out = (float*)d_out;

    char* ws = (char*)d_ws;
    bf16_t* zi     = (bf16_t*)(ws);                 // 1 MB
    bf16_t* zj     = (bf16_t*)(ws + (1u << 20));    // 1 MB
    float*  denoms = (float*)(ws + (2u << 20));     // 32 KB (row ++ col)
    float*  pos    = denoms + 2 * BATCH;            // 16 KB

    normalize_kernel<<<BATCH / 16, 256, 0, stream>>>(emb_i, emb_j, zi, zj, pos, denoms);
    gemm_exp_kernel<<<dim3(NT, NT), 256, 0, stream>>>(zi, zj, denoms, denoms + BATCH);
    finalize_kernel<<<1, 256, 0, stream>>>(denoms, pos, out);
}

// Round 7
// 74.904 us; speedup vs baseline: 1.7857x; 1.0353x over previous
//
#include <hip/hip_runtime.h>
#include <hip/hip_bf16.h>

#define BATCH 4096
#define DIM   128
#define NT    32   // 4096 / 128 tiles per dimension
// TEMP = 0.25 -> 1/T = 4; 4*log2(e):
#define EXP_SCALE 5.770780163555854f

typedef __bf16 bf16_t;
typedef __bf16 bf16x8 __attribute__((ext_vector_type(8)));
typedef float  f32x4  __attribute__((ext_vector_type(4)));

// ---------------------------------------------------------------------------
// Kernel A: normalize emb_i/emb_j rows (fp32 math) -> bf16 zi/zj, pos[k] =
// cos-sim. 16-lane groups, 8 floats/lane, 16 rows per block per matrix.
// Blocks 0..7 zero the denominators (replaces a memset dispatch).
// ---------------------------------------------------------------------------
__global__ __launch_bounds__(256) void normalize_kernel(
    const float* __restrict__ emb_i, const float* __restrict__ emb_j,
    bf16_t* __restrict__ zi, bf16_t* __restrict__ zj, float* __restrict__ pos,
    float* __restrict__ denoms /* 8192 floats */)
{
    const int tid = threadIdx.x;
    if (blockIdx.x < 8) {
        int idx = (blockIdx.x * 256 + tid) * 4;
        *(float4*)&denoms[idx] = make_float4(0.f, 0.f, 0.f, 0.f);
    }

    const int g  = tid >> 4;   // group 0..15 -> row within block
    const int gl = tid & 15;   // lane in group, holds 8 floats
    const int k  = blockIdx.x * 16 + g;

    const float4* pi4 = (const float4*)(emb_i + (size_t)k * DIM);
    const float4* pj4 = (const float4*)(emb_j + (size_t)k * DIM);
    float4 a0 = pi4[gl * 2], a1 = pi4[gl * 2 + 1];
    float4 b0 = pj4[gl * 2], b1 = pj4[gl * 2 + 1];

    float sii = a0.x*a0.x + a0.y*a0.y + a0.z*a0.z + a0.w*a0.w
              + a1.x*a1.x + a1.y*a1.y + a1.z*a1.z + a1.w*a1.w;
    float sjj = b0.x*b0.x + b0.y*b0.y + b0.z*b0.z + b0.w*b0.w
              + b1.x*b1.x + b1.y*b1.y + b1.z*b1.z + b1.w*b1.w;
    float sij = a0.x*b0.x + a0.y*b0.y + a0.z*b0.z + a0.w*b0.w
              + a1.x*b1.x + a1.y*b1.y + a1.z*b1.z + a1.w*b1.w;
#pragma unroll
    for (int m = 1; m < 16; m <<= 1) {
        sii += __shfl_xor(sii, m);
        sjj += __shfl_xor(sjj, m);
        sij += __shfl_xor(sij, m);
    }
    float inv_i = 1.0f / fmaxf(sqrtf(sii), 1e-12f);
    float inv_j = 1.0f / fmaxf(sqrtf(sjj), 1e-12f);

    bf16x8 oi, oj;
    oi[0] = (bf16_t)(a0.x*inv_i); oi[1] = (bf16_t)(a0.y*inv_i);
    oi[2] = (bf16_t)(a0.z*inv_i); oi[3] = (bf16_t)(a0.w*inv_i);
    oi[4] = (bf16_t)(a1.x*inv_i); oi[5] = (bf16_t)(a1.y*inv_i);
    oi[6] = (bf16_t)(a1.z*inv_i); oi[7] = (bf16_t)(a1.w*inv_i);
    oj[0] = (bf16_t)(b0.x*inv_j); oj[1] = (bf16_t)(b0.y*inv_j);
    oj[2] = (bf16_t)(b0.z*inv_j); oj[3] = (bf16_t)(b0.w*inv_j);
    oj[4] = (bf16_t)(b1.x*inv_j); oj[5] = (bf16_t)(b1.y*inv_j);
    oj[6] = (bf16_t)(b1.z*inv_j); oj[7] = (bf16_t)(b1.w*inv_j);
    *(bf16x8*)(zi + (size_t)k * DIM + gl * 8) = oi;
    *(bf16x8*)(zj + (size_t)k * DIM + gl * 8) = oj;

    if (gl == 0) pos[k] = sij * inv_i * inv_j;
}

// ---------------------------------------------------------------------------
// Kernel B (round-4 measured-best structure): 128x128 tile of S = Zi * Zj^T
// per block (grid 32x32). BOTH tiles staged in LDS via coalesced uint4 loads
// (round 6 showed direct global->VGPR A-loads are slightly worse: 256B lane
// stride breaks coalescing). LDS rows padded 128->136 (row stride 272 B =
// free 2-way bank conflicts, 16B-aligned). bf16 MFMA 16x16x32, K=128.
// Epilogue: e = exp(4*s); row sums complete per-wave (shfl) -> 1 atomic per
// row; col sums cross-wave via LDS -> 1 coalesced atomic per col.
// No device fences (round 5: per-block __threadfence() forces L2 writeback
// per block and thrashes the L2-resident tiles, gemm 8 -> 80 us).
// ---------------------------------------------------------------------------
__global__ __launch_bounds__(256) void gemm_exp_kernel(
    const bf16_t* __restrict__ zi, const bf16_t* __restrict__ zj,
    float* __restrict__ rowDenom, float* __restrict__ colDenom)
{
    __shared__ __align__(16) bf16_t zi_s[128][136];
    __shared__ __align__(16) bf16_t zj_s[128][136];
    __shared__ float colRed[4][128];

    const int tid = threadIdx.x;
    const int ti = blockIdx.x, tj = blockIdx.y;

    // Stage 128x128 bf16 of each matrix: 2048 16B-chunks / matrix, 8 iters.
#pragma unroll
    for (int it = 0; it < 8; ++it) {
        int c = it * 256 + tid;
        int row = c >> 4;          // 16 chunks per row
        int col = (c & 15) << 3;   // 8 bf16 per chunk
        *(uint4*)&zi_s[row][col] =
            *(const uint4*)(zi + ((size_t)(ti * 128 + row)) * DIM + col);
        *(uint4*)&zj_s[row][col] =
            *(const uint4*)(zj + ((size_t)(tj * 128 + row)) * DIM + col);
    }
    __syncthreads();

    const int wave = tid >> 6;
    const int lane = tid & 63;
    const int l15  = lane & 15;
    const int quad = lane >> 4;

    const f32x4 vzero = {0.f, 0.f, 0.f, 0.f};
    f32x4 acc[2][8];
#pragma unroll
    for (int rt = 0; rt < 2; ++rt)
#pragma unroll
        for (int ct = 0; ct < 8; ++ct) acc[rt][ct] = vzero;

#pragma unroll
    for (int ks = 0; ks < 4; ++ks) {
        int k0 = ks * 32 + quad * 8;
        bf16x8 afrag[2], bfrag[8];
#pragma unroll
        for (int rt = 0; rt < 2; ++rt)
            afrag[rt] = *(const bf16x8*)&zi_s[(wave * 2 + rt) * 16 + l15][k0];
#pragma unroll
        for (int ct = 0; ct < 8; ++ct)
            bfrag[ct] = *(const bf16x8*)&zj_s[ct * 16 + l15][k0];
#pragma unroll
        for (int rt = 0; rt < 2; ++rt)
#pragma unroll
            for (int ct = 0; ct < 8; ++ct)
                acc[rt][ct] = __builtin_amdgcn_mfma_f32_16x16x32_bf16(
                    afrag[rt], bfrag[ct], acc[rt][ct], 0, 0, 0);
    }

    // Epilogue: exp and partial sums.
    float rowPart[2][4] = {{0.f, 0.f, 0.f, 0.f}, {0.f, 0.f, 0.f, 0.f}};
    float colPart[8]    = {0.f, 0.f, 0.f, 0.f, 0.f, 0.f, 0.f, 0.f};
#pragma unroll
    for (int rt = 0; rt < 2; ++rt)
#pragma unroll
        for (int ct = 0; ct < 8; ++ct)
#pragma unroll
            for (int r = 0; r < 4; ++r) {
                float e = exp2f(acc[rt][ct][r] * EXP_SCALE);
                rowPart[rt][r] += e;   // row = (wave*2+rt)*16 + quad*4 + r
                colPart[ct]    += e;   // col = ct*16 + l15
            }

    // Row sums: each wave's rows see all 128 tile columns; 16-lane shfl
    // reduce completes them. One atomic per row per block.
#pragma unroll
    for (int rt = 0; rt < 2; ++rt)
#pragma unroll
        for (int r = 0; r < 4; ++r) {
            float v = rowPart[rt][r];
            v += __shfl_xor(v, 1);
            v += __shfl_xor(v, 2);
            v += __shfl_xor(v, 4);
            v += __shfl_xor(v, 8);
            if (l15 == 0) {
                int grow = ti * 128 + (wave * 2 + rt) * 16 + quad * 4 + r;
                atomicAdd(&rowDenom[grow], v);
            }
        }

    // Col sums: quad shfl-reduce, cross-wave LDS reduce, coalesced atomics.
#pragma unroll
    for (int ct = 0; ct < 8; ++ct) {
        float v = colPart[ct];
        v += __shfl_xor(v, 16);
        v += __shfl_xor(v, 32);
        if (quad == 0) colRed[wave][ct * 16 + l15] = v;
    }
    __syncthreads();
    if (tid < 128) {
        float s = colRed[0][tid] + colRed[1][tid] + colRed[2][tid] + colRed[3][tid];
        atomicAdd(&colDenom[tj * 128 + tid], s);
    }
}

// ---------------------------------------------------------------------------
// Kernel C: loss = (1/2B) * sum_k [log rowDenom_k + log colDenom_k - 8*pos_k]
// Only 48 KB of reads -> single block is fine.
// ---------------------------------------------------------------------------
__global__ __launch_bounds__(256) void finalize_kernel(
    const float* __restrict__ denoms, const float* __restrict__ pos,
    float* __restrict__ out)
{
    const float* rowDenom = denoms;
    const float* colDenom = denoms + BATCH;
    int tid = threadIdx.x;
    float acc = 0.f;
#pragma unroll
    for (int it = 0; it < 16; ++it) {
        int k = it * 256 + tid;
        acc += logf(rowDenom[k]) + logf(colDenom[k]) - 8.0f * pos[k];
    }
#pragma unroll
    for (int m = 1; m < 64; m <<= 1) acc += __shfl_xor(acc, m);
    __shared__ float red[4];
    if ((tid & 63) == 0) red[tid >> 6] = acc;
    __syncthreads();
    if (tid == 0)
        out[0] = (red[0] + red[1] + red[2] + red[3]) * (1.0f / (2.0f * BATCH));
}

extern "C" void kernel_launch(void* const* d_in, const int* in_sizes, int n_in,
                              void* d_out, int out_size, void* d_ws, size_t ws_size,
                              hipStream_t stream) {
    const float* emb_i = (const float*)d_in[0];
    const float* emb_j = (const float*)d_in[1];
    float* out = (float*)d_out;

    char* ws = (char*)d_ws;
    bf16_t* zi     = (bf16_t*)(ws);                 // 1 MB
    bf16_t* zj     = (bf16_t*)(ws + (1u << 20));    // 1 MB
    float*  denoms = (float*)(ws + (2u << 20));     // 32 KB (row ++ col)
    float*  pos    = denoms + 2 * BATCH;            // 16 KB

    normalize_kernel<<<BATCH / 16, 256, 0, stream>>>(emb_i, emb_j, zi, zj, pos, denoms);
    gemm_exp_kernel<<<dim3(NT, NT), 256, 0, stream>>>(zi, zj, denoms, denoms + BATCH);
    finalize_kernel<<<1, 256, 0, stream>>>(denoms, pos, out);
}